// Round 8
// baseline (521.130 us; speedup 1.0000x reference)
//
#include <hip/hip_runtime.h>
#include <float.h>
#include <stdint.h>

#define DIM 512
#define BM 128
#define BN 128
#define BK 32
#define NSPLIT 64
#define NUM_CLASSES 1000
#define MARGIN 0.04f

typedef unsigned short ushort_t;
typedef __attribute__((ext_vector_type(4))) float fvec4;
typedef __attribute__((ext_vector_type(8))) __bf16 bvec8;
typedef __attribute__((ext_vector_type(4))) int ivec4;

#define AS1 __attribute__((address_space(1)))
#define AS3 __attribute__((address_space(3)))

__device__ inline ushort_t bf16_rne(float f) {
  uint32_t u = __builtin_bit_cast(uint32_t, f);
  uint32_t r = u + 0x7fffu + ((u >> 16) & 1u);
  return (ushort_t)(r >> 16);
}

// ---------- prep: rnorm + f32 -> bf16 (RNE) plane ----------
__global__ __launch_bounds__(256) void prep_bf16(
    const float* __restrict__ src, float* __restrict__ rnorm_out,
    ushort_t* __restrict__ hi, int rows, int scale) {
  int row = blockIdx.x * 4 + (threadIdx.x >> 6);
  int l = threadIdx.x & 63;
  if (row >= rows) return;
  const float4* p = (const float4*)(src + (size_t)row * DIM);
  float4 a = p[l * 2], b = p[l * 2 + 1];
  float rn = 1.0f;
  if (scale) {
    float s = a.x*a.x + a.y*a.y + a.z*a.z + a.w*a.w
            + b.x*b.x + b.y*b.y + b.z*b.z + b.w*b.w;
    #pragma unroll
    for (int off = 1; off < 64; off <<= 1) s += __shfl_xor(s, off, 64);
    rn = 1.0f / fmaxf(sqrtf(s), 1e-12f);
    if (rnorm_out && l == 0) rnorm_out[row] = rn;
  }
  if (!hi) return;
  float v[8] = {a.x*rn, a.y*rn, a.z*rn, a.w*rn, b.x*rn, b.y*rn, b.z*rn, b.w*rn};
  ivec4 hw;
  #pragma unroll
  for (int t = 0; t < 4; ++t) {
    ushort_t h0 = bf16_rne(v[2*t]), h1 = bf16_rne(v[2*t+1]);
    hw[t] = (int)((uint32_t)h0 | ((uint32_t)h1 << 16));
  }
  *(ivec4*)(hi + (size_t)row * DIM + l * 8) = hw;
}

// ---------- screen: bf16 MFMA GEMM (BK=32, R5-proven staging) + reg top-2 ----------
// R7 post-mortem: amdgpu_waves_per_eu(2,2) capped occupancy at 2 waves/SIMD even
// though the 152-reg footprint (88 arch + 64 AGPR) fits 3 (3*152=456 <= 512).
// R8 changes ONLY the max to 3: allocation pressure unchanged (min=2 -> 256-reg
// budget, no R4-style spill), runtime occupancy 2 -> 3 waves/SIMD.
template <bool PRE>
__global__ __launch_bounds__(256)
__attribute__((amdgpu_waves_per_eu(2, 3)))
void nn_mfma(
    const ushort_t* __restrict__ qh, const ushort_t* __restrict__ xh,
    const float* __restrict__ qf, const float* __restrict__ xf,
    const float* __restrict__ rnorm,
    int2* __restrict__ keys, int N, int nPerSplit) {
  __shared__ __align__(1024) char smem[16384];  // A(8K) | B(8K)
  const int tid = threadIdx.x;
  const int l = tid & 63, w = tid >> 6;
  const int wm = w >> 1, wn = w & 1;
  const int lrow = l & 15, lk8 = (l >> 4) * 8;
  const int split = blockIdx.x;
  const int m0 = blockIdx.y * BM;
  const int nStart = split * nPerSplit;
  const int nEnd = min(nStart + nPerSplit, N);

  uint32_t K1[16], K2[16];
  #pragma unroll
  for (int s = 0; s < 16; ++s) { K1[s] = 0u; K2[s] = 0u; }

  const fvec4 zero4 = {0.f, 0.f, 0.f, 0.f};

  #pragma unroll 1
  for (int n0 = nStart; n0 < nEnd; n0 += BN) {
    fvec4 acc[4][4];
    #pragma unroll
    for (int i = 0; i < 4; ++i)
      #pragma unroll
      for (int j = 0; j < 4; ++j) acc[i][j] = zero4;

    #pragma unroll 1
    for (int k0 = 0; k0 < DIM; k0 += BK) {
      if (PRE) {
        #pragma unroll
        for (int b = 0; b < 2; ++b) {
          int f = 2 * w + b;
          int arow = m0 + 16 * f + lrow;
          int brow = min(n0 + 16 * f + lrow, N - 1);
          size_t aoff = (size_t)arow * DIM + k0 + lk8;
          size_t boff = (size_t)brow * DIM + k0 + lk8;
          __builtin_amdgcn_global_load_lds((const AS1 int*)(qh + aoff), (AS3 int*)(smem +    0 + f * 1024), 16, 0, 0);
          __builtin_amdgcn_global_load_lds((const AS1 int*)(xh + boff), (AS3 int*)(smem + 8192 + f * 1024), 16, 0, 0);
        }
      } else {
        #pragma unroll
        for (int u = 0; u < 2; ++u) {
          int unit = tid + 256 * u;            // 0..511
          int row = unit & 127, kg = unit >> 7;
          int base = (row >> 4) * 1024 + kg * 256 + (row & 15) * 16;
          {
            const float* s0 = qf + (size_t)(m0 + row) * DIM + k0 + kg * 8;
            float4 a0 = *(const float4*)s0, a1 = *(const float4*)(s0 + 4);
            float vv[8] = {a0.x,a0.y,a0.z,a0.w,a1.x,a1.y,a1.z,a1.w};
            ivec4 hw;
            #pragma unroll
            for (int t = 0; t < 4; ++t) {
              ushort_t h0 = bf16_rne(vv[2*t]), h1 = bf16_rne(vv[2*t+1]);
              hw[t] = (int)((uint32_t)h0 | ((uint32_t)h1 << 16));
            }
            *(ivec4*)(smem + 0 + base) = hw;
          }
          {
            int gr = min(n0 + row, N - 1);
            float rn = rnorm[gr];
            const float* s0 = xf + (size_t)gr * DIM + k0 + kg * 8;
            float4 a0 = *(const float4*)s0, a1 = *(const float4*)(s0 + 4);
            float vv[8] = {a0.x*rn,a0.y*rn,a0.z*rn,a0.w*rn,a1.x*rn,a1.y*rn,a1.z*rn,a1.w*rn};
            ivec4 hw;
            #pragma unroll
            for (int t = 0; t < 4; ++t) {
              ushort_t h0 = bf16_rne(vv[2*t]), h1 = bf16_rne(vv[2*t+1]);
              hw[t] = (int)((uint32_t)h0 | ((uint32_t)h1 << 16));
            }
            *(ivec4*)(smem + 8192 + base) = hw;
          }
        }
      }
      __syncthreads();  // drains global_load_lds (compiler emits vmcnt(0))

      bvec8 Ah[4], Bh[4];
      #pragma unroll
      for (int i = 0; i < 4; ++i) {
        Ah[i] = __builtin_bit_cast(bvec8, *(const ivec4*)(smem +    0 + (wm*4 + i) * 1024 + l * 16));
        Bh[i] = __builtin_bit_cast(bvec8, *(const ivec4*)(smem + 8192 + (wn*4 + i) * 1024 + l * 16));
      }
      #pragma unroll
      for (int i = 0; i < 4; ++i)
        #pragma unroll
        for (int j = 0; j < 4; ++j)
          acc[i][j] = __builtin_amdgcn_mfma_f32_16x16x32_bf16(Ah[i], Bh[j], acc[i][j], 0, 0, 0);
      __syncthreads();
    }

    // branchless in-register top-2 fold (keys: 21-bit value(+8 bias) | 11-bit inv idx)
    uint32_t msk[4], nb[4];
    #pragma unroll
    for (int j = 0; j < 4; ++j) {
      int n = n0 + wn * 64 + j * 16 + lrow;
      bool valid = n < nEnd;
      msk[j] = valid ? 0xFFFFF800u : 0u;          // invalid -> key = 0 sentinel
      nb[j]  = valid ? (uint32_t)(2047 - (n - nStart)) : 0u;
    }
    #pragma unroll
    for (int i = 0; i < 4; ++i)
      #pragma unroll
      for (int j = 0; j < 4; ++j)
        #pragma unroll
        for (int r = 0; r < 4; ++r) {
          int s = i * 4 + r;
          uint32_t key = (__builtin_bit_cast(uint32_t, acc[i][j][r] + 8.0f) & msk[j]) | nb[j];
          uint32_t lo = min(K1[s], key);
          K1[s] = max(K1[s], key);
          K2[s] = max(K2[s], lo);
        }
  }

  // cross-lane top-2 merge over the 16 lanes sharing each query row
  #pragma unroll
  for (int s = 0; s < 16; ++s) {
    uint32_t k1 = K1[s], k2 = K2[s];
    #pragma unroll
    for (int off = 1; off < 16; off <<= 1) {
      uint32_t o1 = (uint32_t)__shfl_xor((int)k1, off, 64);
      uint32_t o2 = (uint32_t)__shfl_xor((int)k2, off, 64);
      uint32_t nk2 = max(min(k1, o1), max(k2, o2));
      k1 = max(k1, o1);
      k2 = nk2;
    }
    if (lrow == 0) {
      int m = m0 + wm * 64 + (s >> 2) * 16 + (l >> 4) * 4 + (s & 3);
      keys[(size_t)m * (NSPLIT * 2) + split * 2 + wn] = make_int2((int)k1, (int)k2);
    }
  }
}

// ---------- finalize: unpack keys, exact f32 rescore of near-max, one-hot ----------
__global__ __launch_bounds__(256) void finalize_kernel(
    const int2* __restrict__ keys,
    const float* __restrict__ qf, const float* __restrict__ xf,
    const float* __restrict__ rnorm, const int* __restrict__ y,
    int* __restrict__ out, int nPerSplit) {
  int m = blockIdx.x;
  int tid = threadIdx.x, l = tid & 63, w = tid >> 6;
  __shared__ float sv[256]; __shared__ int si[256];
  __shared__ float swm[4];
  __shared__ float swv[4]; __shared__ int swi[4];
  __shared__ int s_label;
  {
    int slot = tid >> 1;                       // split*2 + wn
    int2 kk = keys[(size_t)m * 128 + slot];
    uint32_t k = (tid & 1) ? (uint32_t)kk.y : (uint32_t)kk.x;
    float v; int idx;
    if (k == 0) { v = -FLT_MAX; idx = 0x7fffffff; }
    else {
      v = __builtin_bit_cast(float, k & 0xFFFFF800u) - 8.0f;
      idx = (slot >> 1) * nPerSplit + 2047 - (int)(k & 0x7FFu);
    }
    sv[tid] = v; si[tid] = idx;
  }
  __syncthreads();
  float v = sv[tid];
  #pragma unroll
  for (int off = 1; off < 64; off <<= 1) v = fmaxf(v, __shfl_xor(v, off, 64));
  if (l == 0) swm[w] = v;
  __syncthreads();
  float svmax = fmaxf(fmaxf(swm[0], swm[1]), fmaxf(swm[2], swm[3]));
  float thresh = svmax - MARGIN;
  float bestv = -FLT_MAX; int besti = 0x7fffffff;
  for (int cc = 0; cc < 64; ++cc) {
    int c = w * 64 + cc;
    float av = sv[c]; int idx = si[c];
    if (av < thresh) continue;  // wave-uniform branch
    const float4* qp = (const float4*)(qf + (size_t)m * DIM);
    const float4* xp = (const float4*)(xf + (size_t)idx * DIM);
    float s = 0.f;
    #pragma unroll
    for (int t = 0; t < 2; ++t) {
      float4 qa = qp[l * 2 + t], xa = xp[l * 2 + t];
      s += qa.x*xa.x + qa.y*xa.y + qa.z*xa.z + qa.w*xa.w;
    }
    #pragma unroll
    for (int off = 1; off < 64; off <<= 1) s += __shfl_xor(s, off, 64);
    float ev = s * rnorm[idx];
    if (ev > bestv || (ev == bestv && idx < besti)) { bestv = ev; besti = idx; }
  }
  if (l == 0) { swv[w] = bestv; swi[w] = besti; }
  __syncthreads();
  if (tid == 0) {
    float bv = swv[0]; int bi = swi[0];
    #pragma unroll
    for (int k = 1; k < 4; ++k)
      if (swv[k] > bv || (swv[k] == bv && swi[k] < bi)) { bv = swv[k]; bi = swi[k]; }
    s_label = y[bi];
  }
  __syncthreads();
  int label = s_label;
  for (int c = tid; c < NUM_CLASSES; c += 256)
    out[(size_t)m * NUM_CLASSES + c] = (c == label) ? 1 : 0;
}

extern "C" void kernel_launch(void* const* d_in, const int* in_sizes, int n_in,
                              void* d_out, int out_size, void* d_ws, size_t ws_size,
                              hipStream_t stream) {
  const float* x = (const float*)d_in[0];   // [N, 512]
  const int*   y = (const int*)d_in[1];     // [N]
  const float* q = (const float*)d_in[2];   // [M, 512]
  int N = in_sizes[0] / DIM;                // 100000
  int M = in_sizes[2] / DIM;                // 2048
  int* out = (int*)d_out;

  // workspace layout
  size_t off = 0;
  float* rnorm = (float*)((char*)d_ws + off); off += (((size_t)N * 4 + 1023) / 1024) * 1024;
  int2* keys   = (int2*)((char*)d_ws + off);  off += (size_t)M * NSPLIT * 2 * 8;
  ushort_t* qh = (ushort_t*)((char*)d_ws + off); off += (size_t)M * DIM * 2;
  ushort_t* xh = (ushort_t*)((char*)d_ws + off); off += (size_t)N * DIM * 2;
  bool pre = (ws_size >= off);

  int nPerSplit = (N + NSPLIT - 1) / NSPLIT;  // 1563 (< 2048: fits 11-bit key index)
  dim3 grid(NSPLIT, M / BM);                  // same split -> same XCD (id%8 = split%8)

  if (pre) {
    prep_bf16<<<(N + 3) / 4, 256, 0, stream>>>(x, rnorm, xh, N, 1);
    prep_bf16<<<(M + 3) / 4, 256, 0, stream>>>(q, nullptr, qh, M, 0);
    nn_mfma<true><<<grid, 256, 0, stream>>>(qh, xh, nullptr, nullptr,
                                            rnorm, keys, N, nPerSplit);
  } else {
    prep_bf16<<<(N + 3) / 4, 256, 0, stream>>>(x, rnorm, nullptr, N, 1);
    nn_mfma<false><<<grid, 256, 0, stream>>>(nullptr, nullptr,
                                             q, x, rnorm, keys, N, nPerSplit);
  }
  finalize_kernel<<<M, 256, 0, stream>>>(keys, q, x, rnorm, y, out, nPerSplit);
}

// Round 9
// 457.526 us; speedup vs baseline: 1.1390x; 1.1390x over previous
//
#include <hip/hip_runtime.h>
#include <float.h>
#include <stdint.h>

#define DIM 512
#define BM 128
#define BN 128
#define BK 32
#define NSPLIT 64
#define NUM_CLASSES 1000
#define MARGIN 0.04f

typedef unsigned short ushort_t;
typedef __attribute__((ext_vector_type(4))) float fvec4;
typedef __attribute__((ext_vector_type(8))) __bf16 bvec8;
typedef __attribute__((ext_vector_type(4))) int ivec4;

#define AS1 __attribute__((address_space(1)))
#define AS3 __attribute__((address_space(3)))

__device__ inline ushort_t bf16_rne(float f) {
  uint32_t u = __builtin_bit_cast(uint32_t, f);
  uint32_t r = u + 0x7fffu + ((u >> 16) & 1u);
  return (ushort_t)(r >> 16);
}

// ---------- prep: rnorm + f32 -> bf16 (RNE) plane ----------
__global__ __launch_bounds__(256) void prep_bf16(
    const float* __restrict__ src, float* __restrict__ rnorm_out,
    ushort_t* __restrict__ hi, int rows, int scale) {
  int row = blockIdx.x * 4 + (threadIdx.x >> 6);
  int l = threadIdx.x & 63;
  if (row >= rows) return;
  const float4* p = (const float4*)(src + (size_t)row * DIM);
  float4 a = p[l * 2], b = p[l * 2 + 1];
  float rn = 1.0f;
  if (scale) {
    float s = a.x*a.x + a.y*a.y + a.z*a.z + a.w*a.w
            + b.x*b.x + b.y*b.y + b.z*b.z + b.w*b.w;
    #pragma unroll
    for (int off = 1; off < 64; off <<= 1) s += __shfl_xor(s, off, 64);
    rn = 1.0f / fmaxf(sqrtf(s), 1e-12f);
    if (rnorm_out && l == 0) rnorm_out[row] = rn;
  }
  if (!hi) return;
  float v[8] = {a.x*rn, a.y*rn, a.z*rn, a.w*rn, b.x*rn, b.y*rn, b.z*rn, b.w*rn};
  ivec4 hw;
  #pragma unroll
  for (int t = 0; t < 4; ++t) {
    ushort_t h0 = bf16_rne(v[2*t]), h1 = bf16_rne(v[2*t+1]);
    hw[t] = (int)((uint32_t)h0 | ((uint32_t)h1 << 16));
  }
  *(ivec4*)(hi + (size_t)row * DIM + l * 8) = hw;
}

// ---------- screen: bf16 MFMA GEMM, double-buffered single-barrier pipeline ----------
// R9 (T3 minimal recipe): stage(next) issued at TOP of each k-step into buf[cur^1],
// compute from buf[cur], ONE __syncthreads per k-step (drains vmcnt+lgkm and orders
// buf[cur^1] writes before next step's reads). Pipeline continuous across n0 tiles.
// Fold/merge/packing identical to R7 (proven). waves_per_eu(2,2) kept from R7
// (R8 showed (2,3) tightens codegen without an occupancy payoff).
template <bool PRE>
__global__ __launch_bounds__(256)
__attribute__((amdgpu_waves_per_eu(2, 2)))
void nn_mfma(
    const ushort_t* __restrict__ qh, const ushort_t* __restrict__ xh,
    const float* __restrict__ qf, const float* __restrict__ xf,
    const float* __restrict__ rnorm,
    int2* __restrict__ keys, int N, int nPerSplit) {
  __shared__ __align__(1024) char smem[32768];  // buf0: A|B (16K), buf1: A|B (16K)
  const int tid = threadIdx.x;
  const int l = tid & 63, w = tid >> 6;
  const int wm = w >> 1, wn = w & 1;
  const int lrow = l & 15, lk8 = (l >> 4) * 8;
  const int split = blockIdx.x;
  const int m0 = blockIdx.y * BM;
  const int nStart = split * nPerSplit;
  const int nEnd = min(nStart + nPerSplit, N);

  uint32_t K1[16], K2[16];
  #pragma unroll
  for (int s = 0; s < 16; ++s) { K1[s] = 0u; K2[s] = 0u; }

  const fvec4 zero4 = {0.f, 0.f, 0.f, 0.f};

  // stage one (n0, k0) step into buffer c (lambda keeps size literal = 16)
  auto STAGE = [&](int c, int sn0, int sk0) {
    char* base = smem + c * 16384;
    if (PRE) {
      #pragma unroll
      for (int b = 0; b < 2; ++b) {
        int f = 2 * w + b;
        int arow = m0 + 16 * f + lrow;
        int brow = min(sn0 + 16 * f + lrow, N - 1);
        size_t aoff = (size_t)arow * DIM + sk0 + lk8;
        size_t boff = (size_t)brow * DIM + sk0 + lk8;
        __builtin_amdgcn_global_load_lds((const AS1 int*)(qh + aoff), (AS3 int*)(base +    0 + f * 1024), 16, 0, 0);
        __builtin_amdgcn_global_load_lds((const AS1 int*)(xh + boff), (AS3 int*)(base + 8192 + f * 1024), 16, 0, 0);
      }
    } else {
      #pragma unroll
      for (int u = 0; u < 2; ++u) {
        int unit = tid + 256 * u;            // 0..511
        int row = unit & 127, kg = unit >> 7;
        int boff_l = (row >> 4) * 1024 + kg * 256 + (row & 15) * 16;
        {
          const float* s0 = qf + (size_t)(m0 + row) * DIM + sk0 + kg * 8;
          float4 a0 = *(const float4*)s0, a1 = *(const float4*)(s0 + 4);
          float vv[8] = {a0.x,a0.y,a0.z,a0.w,a1.x,a1.y,a1.z,a1.w};
          ivec4 hw;
          #pragma unroll
          for (int t = 0; t < 4; ++t) {
            ushort_t h0 = bf16_rne(vv[2*t]), h1 = bf16_rne(vv[2*t+1]);
            hw[t] = (int)((uint32_t)h0 | ((uint32_t)h1 << 16));
          }
          *(ivec4*)(base + 0 + boff_l) = hw;
        }
        {
          int gr = min(sn0 + row, N - 1);
          float rn = rnorm[gr];
          const float* s0 = xf + (size_t)gr * DIM + sk0 + kg * 8;
          float4 a0 = *(const float4*)s0, a1 = *(const float4*)(s0 + 4);
          float vv[8] = {a0.x*rn,a0.y*rn,a0.z*rn,a0.w*rn,a1.x*rn,a1.y*rn,a1.z*rn,a1.w*rn};
          ivec4 hw;
          #pragma unroll
          for (int t = 0; t < 4; ++t) {
            ushort_t h0 = bf16_rne(vv[2*t]), h1 = bf16_rne(vv[2*t+1]);
            hw[t] = (int)((uint32_t)h0 | ((uint32_t)h1 << 16));
          }
          *(ivec4*)(base + 8192 + boff_l) = hw;
        }
      }
    }
  };

  int cur = 0;
  STAGE(0, nStart, 0);
  __syncthreads();   // prologue: buf0 ready (vmcnt/lgkm drained by compiler)

  #pragma unroll 1
  for (int n0 = nStart; n0 < nEnd; n0 += BN) {
    fvec4 acc[4][4];
    #pragma unroll
    for (int i = 0; i < 4; ++i)
      #pragma unroll
      for (int j = 0; j < 4; ++j) acc[i][j] = zero4;

    #pragma unroll 1
    for (int k0 = 0; k0 < DIM; k0 += BK) {
      // issue next step's stage into the other buffer (in flight during compute)
      int next_k = k0 + BK, next_n = n0;
      if (next_k == DIM) { next_k = 0; next_n = n0 + BN; }
      if (next_n < nEnd) STAGE(cur ^ 1, next_n, next_k);

      const char* rb = smem + cur * 16384;
      bvec8 Ah[4], Bh[4];
      #pragma unroll
      for (int i = 0; i < 4; ++i) {
        Ah[i] = __builtin_bit_cast(bvec8, *(const ivec4*)(rb +    0 + (wm*4 + i) * 1024 + l * 16));
        Bh[i] = __builtin_bit_cast(bvec8, *(const ivec4*)(rb + 8192 + (wn*4 + i) * 1024 + l * 16));
      }
      #pragma unroll
      for (int i = 0; i < 4; ++i)
        #pragma unroll
        for (int j = 0; j < 4; ++j)
          acc[i][j] = __builtin_amdgcn_mfma_f32_16x16x32_bf16(Ah[i], Bh[j], acc[i][j], 0, 0, 0);

      __syncthreads();  // single barrier/step: orders cur^1 writes vs next reads
      cur ^= 1;
    }

    // branchless in-register top-2 fold (overlaps next tile's in-flight stage)
    uint32_t msk[4], nb[4];
    #pragma unroll
    for (int j = 0; j < 4; ++j) {
      int n = n0 + wn * 64 + j * 16 + lrow;
      bool valid = n < nEnd;
      msk[j] = valid ? 0xFFFFF800u : 0u;          // invalid -> key = 0 sentinel
      nb[j]  = valid ? (uint32_t)(2047 - (n - nStart)) : 0u;
    }
    #pragma unroll
    for (int i = 0; i < 4; ++i)
      #pragma unroll
      for (int j = 0; j < 4; ++j)
        #pragma unroll
        for (int r = 0; r < 4; ++r) {
          int s = i * 4 + r;
          uint32_t key = (__builtin_bit_cast(uint32_t, acc[i][j][r] + 8.0f) & msk[j]) | nb[j];
          uint32_t lo = min(K1[s], key);
          K1[s] = max(K1[s], key);
          K2[s] = max(K2[s], lo);
        }
  }

  // cross-lane top-2 merge over the 16 lanes sharing each query row
  #pragma unroll
  for (int s = 0; s < 16; ++s) {
    uint32_t k1 = K1[s], k2 = K2[s];
    #pragma unroll
    for (int off = 1; off < 16; off <<= 1) {
      uint32_t o1 = (uint32_t)__shfl_xor((int)k1, off, 64);
      uint32_t o2 = (uint32_t)__shfl_xor((int)k2, off, 64);
      uint32_t nk2 = max(min(k1, o1), max(k2, o2));
      k1 = max(k1, o1);
      k2 = nk2;
    }
    if (lrow == 0) {
      int m = m0 + wm * 64 + (s >> 2) * 16 + (l >> 4) * 4 + (s & 3);
      keys[(size_t)m * (NSPLIT * 2) + split * 2 + wn] = make_int2((int)k1, (int)k2);
    }
  }
}

// ---------- finalize: unpack keys, exact f32 rescore of near-max, one-hot ----------
__global__ __launch_bounds__(256) void finalize_kernel(
    const int2* __restrict__ keys,
    const float* __restrict__ qf, const float* __restrict__ xf,
    const float* __restrict__ rnorm, const int* __restrict__ y,
    int* __restrict__ out, int nPerSplit) {
  int m = blockIdx.x;
  int tid = threadIdx.x, l = tid & 63, w = tid >> 6;
  __shared__ float sv[256]; __shared__ int si[256];
  __shared__ float swm[4];
  __shared__ float swv[4]; __shared__ int swi[4];
  __shared__ int s_label;
  {
    int slot = tid >> 1;                       // split*2 + wn
    int2 kk = keys[(size_t)m * 128 + slot];
    uint32_t k = (tid & 1) ? (uint32_t)kk.y : (uint32_t)kk.x;
    float v; int idx;
    if (k == 0) { v = -FLT_MAX; idx = 0x7fffffff; }
    else {
      v = __builtin_bit_cast(float, k & 0xFFFFF800u) - 8.0f;
      idx = (slot >> 1) * nPerSplit + 2047 - (int)(k & 0x7FFu);
    }
    sv[tid] = v; si[tid] = idx;
  }
  __syncthreads();
  float v = sv[tid];
  #pragma unroll
  for (int off = 1; off < 64; off <<= 1) v = fmaxf(v, __shfl_xor(v, off, 64));
  if (l == 0) swm[w] = v;
  __syncthreads();
  float svmax = fmaxf(fmaxf(swm[0], swm[1]), fmaxf(swm[2], swm[3]));
  float thresh = svmax - MARGIN;
  float bestv = -FLT_MAX; int besti = 0x7fffffff;
  for (int cc = 0; cc < 64; ++cc) {
    int c = w * 64 + cc;
    float av = sv[c]; int idx = si[c];
    if (av < thresh) continue;  // wave-uniform branch
    const float4* qp = (const float4*)(qf + (size_t)m * DIM);
    const float4* xp = (const float4*)(xf + (size_t)idx * DIM);
    float s = 0.f;
    #pragma unroll
    for (int t = 0; t < 2; ++t) {
      float4 qa = qp[l * 2 + t], xa = xp[l * 2 + t];
      s += qa.x*xa.x + qa.y*xa.y + qa.z*xa.z + qa.w*xa.w;
    }
    #pragma unroll
    for (int off = 1; off < 64; off <<= 1) s += __shfl_xor(s, off, 64);
    float ev = s * rnorm[idx];
    if (ev > bestv || (ev == bestv && idx < besti)) { bestv = ev; besti = idx; }
  }
  if (l == 0) { swv[w] = bestv; swi[w] = besti; }
  __syncthreads();
  if (tid == 0) {
    float bv = swv[0]; int bi = swi[0];
    #pragma unroll
    for (int k = 1; k < 4; ++k)
      if (swv[k] > bv || (swv[k] == bv && swi[k] < bi)) { bv = swv[k]; bi = swi[k]; }
    s_label = y[bi];
  }
  __syncthreads();
  int label = s_label;
  for (int c = tid; c < NUM_CLASSES; c += 256)
    out[(size_t)m * NUM_CLASSES + c] = (c == label) ? 1 : 0;
}

extern "C" void kernel_launch(void* const* d_in, const int* in_sizes, int n_in,
                              void* d_out, int out_size, void* d_ws, size_t ws_size,
                              hipStream_t stream) {
  const float* x = (const float*)d_in[0];   // [N, 512]
  const int*   y = (const int*)d_in[1];     // [N]
  const float* q = (const float*)d_in[2];   // [M, 512]
  int N = in_sizes[0] / DIM;                // 100000
  int M = in_sizes[2] / DIM;                // 2048
  int* out = (int*)d_out;

  // workspace layout
  size_t off = 0;
  float* rnorm = (float*)((char*)d_ws + off); off += (((size_t)N * 4 + 1023) / 1024) * 1024;
  int2* keys   = (int2*)((char*)d_ws + off);  off += (size_t)M * NSPLIT * 2 * 8;
  ushort_t* qh = (ushort_t*)((char*)d_ws + off); off += (size_t)M * DIM * 2;
  ushort_t* xh = (ushort_t*)((char*)d_ws + off); off += (size_t)N * DIM * 2;
  bool pre = (ws_size >= off);

  int nPerSplit = (N + NSPLIT - 1) / NSPLIT;  // 1563 (< 2048: fits 11-bit key index)
  dim3 grid(NSPLIT, M / BM);                  // same split -> same XCD (id%8 = split%8)

  if (pre) {
    prep_bf16<<<(N + 3) / 4, 256, 0, stream>>>(x, rnorm, xh, N, 1);
    prep_bf16<<<(M + 3) / 4, 256, 0, stream>>>(q, nullptr, qh, M, 0);
    nn_mfma<true><<<grid, 256, 0, stream>>>(qh, xh, nullptr, nullptr,
                                            rnorm, keys, N, nPerSplit);
  } else {
    prep_bf16<<<(N + 3) / 4, 256, 0, stream>>>(x, rnorm, nullptr, N, 1);
    nn_mfma<false><<<grid, 256, 0, stream>>>(nullptr, nullptr,
                                             q, x, rnorm, keys, N, nPerSplit);
  }
  finalize_kernel<<<M, 256, 0, stream>>>(keys, q, x, rnorm, y, out, nPerSplit);
}

// Round 10
// 362.921 us; speedup vs baseline: 1.4359x; 1.2607x over previous
//
#include <hip/hip_runtime.h>
#include <float.h>
#include <stdint.h>

#define DIM 512
#define BM 256
#define BN 128
#define BK 32
#define NSPLIT 64
#define NUM_CLASSES 1000
#define MARGIN 0.04f

typedef unsigned short ushort_t;
typedef __attribute__((ext_vector_type(4))) float fvec4;
typedef __attribute__((ext_vector_type(8))) __bf16 bvec8;
typedef __attribute__((ext_vector_type(4))) int ivec4;

#define AS1 __attribute__((address_space(1)))
#define AS3 __attribute__((address_space(3)))

__device__ inline ushort_t bf16_rne(float f) {
  uint32_t u = __builtin_bit_cast(uint32_t, f);
  uint32_t r = u + 0x7fffu + ((u >> 16) & 1u);
  return (ushort_t)(r >> 16);
}

// ---------- prep: rnorm + f32 -> bf16 (RNE) plane ----------
__global__ __launch_bounds__(256) void prep_bf16(
    const float* __restrict__ src, float* __restrict__ rnorm_out,
    ushort_t* __restrict__ hi, int rows, int scale) {
  int row = blockIdx.x * 4 + (threadIdx.x >> 6);
  int l = threadIdx.x & 63;
  if (row >= rows) return;
  const float4* p = (const float4*)(src + (size_t)row * DIM);
  float4 a = p[l * 2], b = p[l * 2 + 1];
  float rn = 1.0f;
  if (scale) {
    float s = a.x*a.x + a.y*a.y + a.z*a.z + a.w*a.w
            + b.x*b.x + b.y*b.y + b.z*b.z + b.w*b.w;
    #pragma unroll
    for (int off = 1; off < 64; off <<= 1) s += __shfl_xor(s, off, 64);
    rn = 1.0f / fmaxf(sqrtf(s), 1e-12f);
    if (rnorm_out && l == 0) rnorm_out[row] = rn;
  }
  if (!hi) return;
  float v[8] = {a.x*rn, a.y*rn, a.z*rn, a.w*rn, b.x*rn, b.y*rn, b.z*rn, b.w*rn};
  ivec4 hw;
  #pragma unroll
  for (int t = 0; t < 4; ++t) {
    ushort_t h0 = bf16_rne(v[2*t]), h1 = bf16_rne(v[2*t+1]);
    hw[t] = (int)((uint32_t)h0 | ((uint32_t)h1 << 16));
  }
  *(ivec4*)(hi + (size_t)row * DIM + l * 8) = hw;
}

// ---------- screen: bf16 MFMA GEMM, 64x128 per-wave tile (LDS-traffic fix) ----------
// R9 diagnosis: 8 ds_read_b128/wave/step @ ~12cyc made LDS the binding pipe
// (predicted MfmaUtil 20.2%, observed 20.6%). R10: per-wave tile 64x64 -> 64x128
// (BM=256, 4 waves own 64 rows x full BN): 12 reads per 32 MFMA vs 8 per 16 ->
// 1.33x less LDS traffic per FLOP. Sync structure/blob layout/fold = R9-verbatim.
// acc 4x8 fvec4 (128 AGPR) + ~100 arch VGPR fits the 256 budget of (2,2).
template <bool PRE>
__global__ __launch_bounds__(256)
__attribute__((amdgpu_waves_per_eu(2, 2)))
void nn_mfma(
    const ushort_t* __restrict__ qh, const ushort_t* __restrict__ xh,
    const float* __restrict__ qf, const float* __restrict__ xf,
    const float* __restrict__ rnorm,
    int2* __restrict__ keys, int N, int nPerSplit) {
  __shared__ __align__(1024) char smem[49152];  // 2 bufs x (A 16K | B 8K)
  const int tid = threadIdx.x;
  const int l = tid & 63, wv = tid >> 6;        // wave owns rows wv*64..wv*64+63
  const int lrow = l & 15, lk8 = (l >> 4) * 8;
  const int split = blockIdx.x;
  const int m0 = blockIdx.y * BM;
  const int nStart = split * nPerSplit;
  const int nEnd = min(nStart + nPerSplit, N);

  uint32_t K1[16], K2[16];
  #pragma unroll
  for (int s = 0; s < 16; ++s) { K1[s] = 0u; K2[s] = 0u; }

  const fvec4 zero4 = {0.f, 0.f, 0.f, 0.f};

  // stage one (n0, k0) step into buffer c: A blobs 4wv..4wv+3, B blobs 2wv..2wv+1
  auto STAGE = [&](int c, int sn0, int sk0) {
    char* base = smem + c * 24576;
    if (PRE) {
      #pragma unroll
      for (int t = 0; t < 4; ++t) {
        int f = 4 * wv + t;
        int arow = m0 + 16 * f + lrow;
        size_t aoff = (size_t)arow * DIM + sk0 + lk8;
        __builtin_amdgcn_global_load_lds((const AS1 int*)(qh + aoff), (AS3 int*)(base + f * 1024), 16, 0, 0);
      }
      #pragma unroll
      for (int t = 0; t < 2; ++t) {
        int g = 2 * wv + t;
        int brow = min(sn0 + 16 * g + lrow, N - 1);
        size_t boff = (size_t)brow * DIM + sk0 + lk8;
        __builtin_amdgcn_global_load_lds((const AS1 int*)(xh + boff), (AS3 int*)(base + 16384 + g * 1024), 16, 0, 0);
      }
    } else {
      #pragma unroll
      for (int u = 0; u < 6; ++u) {
        int unit = tid + 256 * u;            // 0..1535: A units 0..1023, B 1024..1535
        if (unit < 1024) {
          int row = unit >> 2, kg = unit & 3;
          int boff_l = (row >> 4) * 1024 + kg * 256 + (row & 15) * 16;
          const float* s0 = qf + (size_t)(m0 + row) * DIM + sk0 + kg * 8;
          float4 a0 = *(const float4*)s0, a1 = *(const float4*)(s0 + 4);
          float vv[8] = {a0.x,a0.y,a0.z,a0.w,a1.x,a1.y,a1.z,a1.w};
          ivec4 hw;
          #pragma unroll
          for (int t = 0; t < 4; ++t) {
            ushort_t h0 = bf16_rne(vv[2*t]), h1 = bf16_rne(vv[2*t+1]);
            hw[t] = (int)((uint32_t)h0 | ((uint32_t)h1 << 16));
          }
          *(ivec4*)(base + boff_l) = hw;
        } else {
          int u2 = unit - 1024;
          int row = u2 >> 2, kg = u2 & 3;
          int boff_l = 16384 + (row >> 4) * 1024 + kg * 256 + (row & 15) * 16;
          int gr = min(sn0 + row, N - 1);
          float rn = rnorm[gr];
          const float* s0 = xf + (size_t)gr * DIM + sk0 + kg * 8;
          float4 a0 = *(const float4*)s0, a1 = *(const float4*)(s0 + 4);
          float vv[8] = {a0.x*rn,a0.y*rn,a0.z*rn,a0.w*rn,a1.x*rn,a1.y*rn,a1.z*rn,a1.w*rn};
          ivec4 hw;
          #pragma unroll
          for (int t = 0; t < 4; ++t) {
            ushort_t h0 = bf16_rne(vv[2*t]), h1 = bf16_rne(vv[2*t+1]);
            hw[t] = (int)((uint32_t)h0 | ((uint32_t)h1 << 16));
          }
          *(ivec4*)(base + boff_l) = hw;
        }
      }
    }
  };

  int cur = 0;
  STAGE(0, nStart, 0);
  __syncthreads();   // prologue: buf0 ready

  #pragma unroll 1
  for (int n0 = nStart; n0 < nEnd; n0 += BN) {
    fvec4 acc[4][8];
    #pragma unroll
    for (int i = 0; i < 4; ++i)
      #pragma unroll
      for (int j = 0; j < 8; ++j) acc[i][j] = zero4;

    #pragma unroll 1
    for (int k0 = 0; k0 < DIM; k0 += BK) {
      // issue next step's stage into the other buffer (in flight during compute)
      int next_k = k0 + BK, next_n = n0;
      if (next_k == DIM) { next_k = 0; next_n = n0 + BN; }
      if (next_n < nEnd) STAGE(cur ^ 1, next_n, next_k);

      const char* rb = smem + cur * 24576;
      bvec8 Ah[4], Bh[8];
      #pragma unroll
      for (int i = 0; i < 4; ++i)
        Ah[i] = __builtin_bit_cast(bvec8, *(const ivec4*)(rb + (wv*4 + i) * 1024 + l * 16));
      #pragma unroll
      for (int j = 0; j < 8; ++j)
        Bh[j] = __builtin_bit_cast(bvec8, *(const ivec4*)(rb + 16384 + j * 1024 + l * 16));
      #pragma unroll
      for (int i = 0; i < 4; ++i)
        #pragma unroll
        for (int j = 0; j < 8; ++j)
          acc[i][j] = __builtin_amdgcn_mfma_f32_16x16x32_bf16(Ah[i], Bh[j], acc[i][j], 0, 0, 0);

      __syncthreads();  // single barrier/step: orders cur^1 writes vs next reads
      cur ^= 1;
    }

    // branchless in-register top-2 fold (keys: 21-bit value(+8 bias) | 11-bit inv idx)
    uint32_t msk[8], nb[8];
    #pragma unroll
    for (int j = 0; j < 8; ++j) {
      int n = n0 + j * 16 + lrow;
      bool valid = n < nEnd;
      msk[j] = valid ? 0xFFFFF800u : 0u;          // invalid -> key = 0 sentinel
      nb[j]  = valid ? (uint32_t)(2047 - (n - nStart)) : 0u;
    }
    #pragma unroll
    for (int i = 0; i < 4; ++i)
      #pragma unroll
      for (int j = 0; j < 8; ++j)
        #pragma unroll
        for (int r = 0; r < 4; ++r) {
          int s = i * 4 + r;
          uint32_t key = (__builtin_bit_cast(uint32_t, acc[i][j][r] + 8.0f) & msk[j]) | nb[j];
          uint32_t lo = min(K1[s], key);
          K1[s] = max(K1[s], key);
          K2[s] = max(K2[s], lo);
        }
  }

  // cross-lane top-2 merge over the 16 lanes sharing each query row
  #pragma unroll
  for (int s = 0; s < 16; ++s) {
    uint32_t k1 = K1[s], k2 = K2[s];
    #pragma unroll
    for (int off = 1; off < 16; off <<= 1) {
      uint32_t o1 = (uint32_t)__shfl_xor((int)k1, off, 64);
      uint32_t o2 = (uint32_t)__shfl_xor((int)k2, off, 64);
      uint32_t nk2 = max(min(k1, o1), max(k2, o2));
      k1 = max(k1, o1);
      k2 = nk2;
    }
    if (lrow == 0) {
      int m = m0 + wv * 64 + (s >> 2) * 16 + (l >> 4) * 4 + (s & 3);
      keys[(size_t)m * NSPLIT + split] = make_int2((int)k1, (int)k2);
    }
  }
}

// ---------- finalize: unpack keys, exact f32 rescore of near-max, one-hot ----------
__global__ __launch_bounds__(256) void finalize_kernel(
    const int2* __restrict__ keys,
    const float* __restrict__ qf, const float* __restrict__ xf,
    const float* __restrict__ rnorm, const int* __restrict__ y,
    int* __restrict__ out, int nPerSplit) {
  int m = blockIdx.x;
  int tid = threadIdx.x, l = tid & 63, w = tid >> 6;
  __shared__ float sv[256]; __shared__ int si[256];
  __shared__ float swm[4];
  __shared__ float swv[4]; __shared__ int swi[4];
  __shared__ int s_label;
  if (tid < 128) {
    int slot = tid >> 1;                       // = split
    int2 kk = keys[(size_t)m * NSPLIT + slot];
    uint32_t k = (tid & 1) ? (uint32_t)kk.y : (uint32_t)kk.x;
    float v; int idx;
    if (k == 0) { v = -FLT_MAX; idx = 0x7fffffff; }
    else {
      v = __builtin_bit_cast(float, k & 0xFFFFF800u) - 8.0f;
      idx = slot * nPerSplit + 2047 - (int)(k & 0x7FFu);
    }
    sv[tid] = v; si[tid] = idx;
  } else { sv[tid] = -FLT_MAX; si[tid] = 0x7fffffff; }
  __syncthreads();
  float v = sv[tid];
  #pragma unroll
  for (int off = 1; off < 64; off <<= 1) v = fmaxf(v, __shfl_xor(v, off, 64));
  if (l == 0) swm[w] = v;
  __syncthreads();
  float svmax = fmaxf(fmaxf(swm[0], swm[1]), fmaxf(swm[2], swm[3]));
  float thresh = svmax - MARGIN;
  float bestv = -FLT_MAX; int besti = 0x7fffffff;
  for (int cc = 0; cc < 64; ++cc) {
    int c = w * 64 + cc;
    float av = sv[c]; int idx = si[c];
    if (av < thresh) continue;  // wave-uniform branch
    const float4* qp = (const float4*)(qf + (size_t)m * DIM);
    const float4* xp = (const float4*)(xf + (size_t)idx * DIM);
    float s = 0.f;
    #pragma unroll
    for (int t = 0; t < 2; ++t) {
      float4 qa = qp[l * 2 + t], xa = xp[l * 2 + t];
      s += qa.x*xa.x + qa.y*xa.y + qa.z*xa.z + qa.w*xa.w;
    }
    #pragma unroll
    for (int off = 1; off < 64; off <<= 1) s += __shfl_xor(s, off, 64);
    float ev = s * rnorm[idx];
    if (ev > bestv || (ev == bestv && idx < besti)) { bestv = ev; besti = idx; }
  }
  if (l == 0) { swv[w] = bestv; swi[w] = besti; }
  __syncthreads();
  if (tid == 0) {
    float bv = swv[0]; int bi = swi[0];
    #pragma unroll
    for (int k = 1; k < 4; ++k)
      if (swv[k] > bv || (swv[k] == bv && swi[k] < bi)) { bv = swv[k]; bi = swi[k]; }
    s_label = y[bi];
  }
  __syncthreads();
  int label = s_label;
  for (int c = tid; c < NUM_CLASSES; c += 256)
    out[(size_t)m * NUM_CLASSES + c] = (c == label) ? 1 : 0;
}

extern "C" void kernel_launch(void* const* d_in, const int* in_sizes, int n_in,
                              void* d_out, int out_size, void* d_ws, size_t ws_size,
                              hipStream_t stream) {
  const float* x = (const float*)d_in[0];   // [N, 512]
  const int*   y = (const int*)d_in[1];     // [N]
  const float* q = (const float*)d_in[2];   // [M, 512]
  int N = in_sizes[0] / DIM;                // 100000
  int M = in_sizes[2] / DIM;                // 2048
  int* out = (int*)d_out;

  // workspace layout
  size_t off = 0;
  float* rnorm = (float*)((char*)d_ws + off); off += (((size_t)N * 4 + 1023) / 1024) * 1024;
  int2* keys   = (int2*)((char*)d_ws + off);  off += (size_t)M * NSPLIT * 8;
  ushort_t* qh = (ushort_t*)((char*)d_ws + off); off += (size_t)M * DIM * 2;
  ushort_t* xh = (ushort_t*)((char*)d_ws + off); off += (size_t)N * DIM * 2;
  bool pre = (ws_size >= off);

  int nPerSplit = (N + NSPLIT - 1) / NSPLIT;  // 1563 (< 2048: fits 11-bit key index)
  dim3 grid(NSPLIT, M / BM);                  // 64 x 8 = 512 blocks = 2/CU exactly

  if (pre) {
    prep_bf16<<<(N + 3) / 4, 256, 0, stream>>>(x, rnorm, xh, N, 1);
    prep_bf16<<<(M + 3) / 4, 256, 0, stream>>>(q, nullptr, qh, M, 0);
    nn_mfma<true><<<grid, 256, 0, stream>>>(qh, xh, nullptr, nullptr,
                                            rnorm, keys, N, nPerSplit);
  } else {
    prep_bf16<<<(N + 3) / 4, 256, 0, stream>>>(x, rnorm, nullptr, N, 1);
    nn_mfma<false><<<grid, 256, 0, stream>>>(nullptr, nullptr,
                                             q, x, rnorm, keys, N, nPerSplit);
  }
  finalize_kernel<<<M, 256, 0, stream>>>(keys, q, x, rnorm, y, out, nPerSplit);
}